// Round 3
// baseline (102.414 us; speedup 1.0000x reference)
//
#include <hip/hip_runtime.h>

#define RATE 0.001f

typedef float f2 __attribute__((ext_vector_type(2)));
typedef float f4 __attribute__((ext_vector_type(4)));

static __device__ __forceinline__ f2 splat2(float v) { f2 r; r.x = v; r.y = v; return r; }
static __device__ __forceinline__ f2 vfma2(f2 a, f2 b, f2 c) { return __builtin_elementwise_fma(a, b, c); }

// Fused Hebbian layer, one kernel per layer.
// Block = 512 threads = 8 waves; block owns output neuron o and ALL 8 batch rows.
// Wave w: b-pair pr = w&3 (rows 2pr, 2pr+1), i-half = w>>2.
// Each wave streams HALF of w-row for 2 batch rows -> per-o w-row cache traffic
// drops 4x vs previous (16 full-row streams -> 8 half-row streams).
// c2b is folded into the t-accumulator init (t.x = c2b), removing the separate
// rowsum(a) reduction entirely:
//   shift_i = (sum_h relu(a_i p_h + w_oi q_h + vj r_h + c1b_h) c2w_h + c2b)*scale
//   out[b,o] = vj + sum_i a_i * shift_i,  vj = relu(dot(a_b,w_o)+bias_o)
// Cross-wave (i-half) combines via tiny LDS arrays.
template<int I>
__global__ __launch_bounds__(512, 4) void hebb_layer(
    const float* __restrict__ vi,    // (8, I)
    const float* __restrict__ w,     // (O, I)
    const float* __restrict__ bias,  // (O,)
    const float* __restrict__ c1w,   // (8, 3): p,q,r
    const float* __restrict__ c1b,   // (8,)
    const float* __restrict__ c2w,   // (8,)
    const float* __restrict__ c2b_p, // scalar
    const int*   __restrict__ bn_p,  // scalar batch_num
    float* __restrict__ out,         // (8, O)
    int O)
{
    const int o    = blockIdx.x;
    const int tid  = threadIdx.x;
    const int lane = tid & 63;
    const int wv8  = tid >> 6;       // wave 0..7
    const int pr   = wv8 & 3;        // b-pair: rows 2pr, 2pr+1
    const int half = wv8 >> 2;       // i-half 0/1

    constexpr int HALF  = I / 2;
    constexpr int ITERS = HALF / 256;   // 64 lanes * 4 floats per iter

    const float* __restrict__ wrow = w  + (size_t)o * I        + (size_t)half * HALF;
    const float* __restrict__ a0   = vi + (size_t)(2*pr) * I   + (size_t)half * HALF;
    const float* __restrict__ a1   = a0 + I;

    __shared__ float dotp[8][2];   // [wave][b-of-pair] partial dots
    __shared__ float accp[8][2];   // [wave][b-of-pair] partial meta sums

    // ---- pass 1: partial dots for 2 batch rows over this wave's i-half ----
    float d0 = 0.f, d1 = 0.f;
#pragma unroll
    for (int it = 0; it < ITERS; ++it) {
        const int base = it * 256 + lane * 4;
        const f4 wv4 = *(const f4*)(wrow + base);
        const f4 a0v = *(const f4*)(a0 + base);
        const f4 a1v = *(const f4*)(a1 + base);
#pragma unroll
        for (int e = 0; e < 4; ++e) {
            d0 = fmaf(a0v[e], wv4[e], d0);
            d1 = fmaf(a1v[e], wv4[e], d1);
        }
    }
#pragma unroll
    for (int off = 1; off < 64; off <<= 1) {
        d0 += __shfl_xor(d0, off, 64);
        d1 += __shfl_xor(d1, off, 64);
    }
    if (lane == 0) { dotp[wv8][0] = d0; dotp[wv8][1] = d1; }
    __syncthreads();

    const float bo   = bias[o];
    const float vj0  = fmaxf(dotp[pr][0] + dotp[pr + 4][0] + bo, 0.f);
    const float vj1  = fmaxf(dotp[pr][1] + dotp[pr + 4][1] + bo, 0.f);
    const float c2b  = *c2b_p;

    // steady-state constants: p,q,c2 packed pairs; K[h] = vj*r_h + c1b_h per b
    f2 p2[4], q2[4], c22[4], K0[4], K1[4];
#pragma unroll
    for (int j = 0; j < 4; ++j) {
        const float rA = c1w[(2*j)*3 + 2], rB = c1w[(2*j+1)*3 + 2];
        const float cA = c1b[2*j],         cB = c1b[2*j+1];
        p2[j].x  = c1w[(2*j)*3 + 0];  p2[j].y  = c1w[(2*j+1)*3 + 0];
        q2[j].x  = c1w[(2*j)*3 + 1];  q2[j].y  = c1w[(2*j+1)*3 + 1];
        c22[j].x = c2w[2*j];          c22[j].y = c2w[2*j+1];
        K0[j].x  = fmaf(vj0, rA, cA); K0[j].y  = fmaf(vj0, rB, cB);
        K1[j].x  = fmaf(vj1, rA, cA); K1[j].y  = fmaf(vj1, rB, cB);
    }

    // ---- pass 2: meta-MLP accumulation for both batch rows (streams cache-hot) ----
    f2 acc0 = splat2(0.f), acc1 = splat2(0.f);
#pragma unroll
    for (int it = 0; it < ITERS; ++it) {
        const int base = it * 256 + lane * 4;
        const f4 wv4 = *(const f4*)(wrow + base);
        const f4 a0v = *(const f4*)(a0 + base);
        const f4 a1v = *(const f4*)(a1 + base);
#pragma unroll
        for (int e = 0; e < 4; ++e) {
            const f2 wvE = splat2(wv4[e]);
            // b = 2*pr
            {
                const f2 aE = splat2(a0v[e]);
                f2 t; t.x = c2b; t.y = 0.f;   // c2b folded into accumulator init
#pragma unroll
                for (int j = 0; j < 4; ++j) {
                    f2 z = vfma2(wvE, q2[j], K0[j]);
                    z = vfma2(aE, p2[j], z);
                    const f2 u = __builtin_elementwise_max(z, splat2(0.f));
                    t = vfma2(u, c22[j], t);
                }
                acc0 = vfma2(aE, t, acc0);
            }
            // b = 2*pr+1
            {
                const f2 aE = splat2(a1v[e]);
                f2 t; t.x = c2b; t.y = 0.f;
#pragma unroll
                for (int j = 0; j < 4; ++j) {
                    f2 z = vfma2(wvE, q2[j], K1[j]);
                    z = vfma2(aE, p2[j], z);
                    const f2 u = __builtin_elementwise_max(z, splat2(0.f));
                    t = vfma2(u, c22[j], t);
                }
                acc1 = vfma2(aE, t, acc1);
            }
        }
    }
    float r0 = acc0.x + acc0.y, r1 = acc1.x + acc1.y;
#pragma unroll
    for (int off = 1; off < 64; off <<= 1) {
        r0 += __shfl_xor(r0, off, 64);
        r1 += __shfl_xor(r1, off, 64);
    }
    if (lane == 0) { accp[wv8][0] = r0; accp[wv8][1] = r1; }
    __syncthreads();

    // ---- tail: combine i-halves, write 8 outputs ----
    if (tid < 8) {
        const int b = tid, p = b >> 1, bb = b & 1;
        const float dt = dotp[p][bb] + dotp[p + 4][bb];
        const float vj = fmaxf(dt + bias[o], 0.f);
        const float r  = accp[p][bb] + accp[p + 4][bb];
        const float scale = RATE / (float)(*bn_p);
        out[(size_t)b * O + o] = vj + scale * r;
    }
}

extern "C" void kernel_launch(void* const* d_in, const int* in_sizes, int n_in,
                              void* d_out, int out_size, void* d_ws, size_t ws_size,
                              hipStream_t stream) {
    const float* x   = (const float*)d_in[0];   // (8, 1024)
    const float* w1  = (const float*)d_in[1];   // (2048, 1024)
    const float* b1  = (const float*)d_in[2];   // (2048,)
    const float* w2  = (const float*)d_in[3];   // (512, 2048)
    const float* b2  = (const float*)d_in[4];   // (512,)
    const float* c1w = (const float*)d_in[5];   // (8, 3)
    const float* c1b = (const float*)d_in[6];   // (8,)
    const float* c2w = (const float*)d_in[7];   // (8,)
    const float* c2b = (const float*)d_in[8];   // ()
    const int*   bn  = (const int*)d_in[9];     // scalar

    float* out = (float*)d_out;                 // (8, 512) fp32
    float* mid = (float*)d_ws;                  // (8, 2048) fp32 = 64 KB

    hebb_layer<1024><<<2048, 512, 0, stream>>>(x,   w1, b1, c1w, c1b, c2w, c2b, bn, mid, 2048);
    hebb_layer<2048><<<512,  512, 0, stream>>>(mid, w2, b2, c1w, c1b, c2w, c2b, bn, out, 512);
}